// Round 11
// baseline (532.289 us; speedup 1.0000x reference)
//
#include <hip/hip_runtime.h>
#include <hip/hip_bf16.h>

// RGCN hetero layer: out[n,f] = sum over r, edges (s->n) in r of feat[s,:] @ W[r]
//
// R5/R7 evidence: 194-199us flat with/without LDS; WRITE==atomic volume
// (204.8MB); atomic rate 264G/s == TCC dword-atomic ceiling. => atomic-bound.
// R8: counting-sort edges by (dst>>7, rel) into d_ws, then one block per
// 128-node bucket accumulates into a 32KB LDS accumulator (LDS atomics) and
// writes each out row ONCE with plain coalesced stores. Global atomics drop
// 51.2M -> ~1.6M (hist + slot alloc, cache-resident). Inner per-edge matmul
// identical to R7 (wreg W-columns + readlane-uniform gather).

#define BUCKET_SHIFT 7
#define BUCKET_NODES 128            // 1 << BUCKET_SHIFT
#define REL_SHIFT 20                // dst occupies low 20 bits (N < 2^20)

// ---------------- hist ----------------
__global__ __launch_bounds__(256) void k_hist(
    const int* __restrict__ edst, unsigned* __restrict__ hist, int E, int R)
{
    const int e = blockIdx.x * 256 + threadIdx.x;
    const int r = blockIdx.y;
    if (e < E) {
        const unsigned d = (unsigned)edst[(size_t)r * E + e];
        atomicAdd(&hist[(d >> BUCKET_SHIFT) * R + r], 1u);
    }
}

// ---------------- scan ----------------
__global__ __launch_bounds__(256) void k_scan(
    const unsigned* __restrict__ hist, unsigned* __restrict__ base,
    unsigned* __restrict__ cursor, int nbins)
{
    __shared__ unsigned psum[256];
    const int t  = threadIdx.x;
    const int C  = (nbins + 255) / 256;
    const int i0 = t * C, i1 = min(i0 + C, nbins);
    unsigned s = 0;
    for (int i = i0; i < i1; ++i) s += hist[i];
    psum[t] = s;
    __syncthreads();
    if (t == 0) {
        unsigned run = 0;
        for (int i = 0; i < 256; ++i) { unsigned v = psum[i]; psum[i] = run; run += v; }
        base[nbins] = run;
    }
    __syncthreads();
    unsigned run = psum[t];
    for (int i = i0; i < i1; ++i) { base[i] = run; cursor[i] = run; run += hist[i]; }
}

// ---------------- scatter ----------------
__global__ __launch_bounds__(256) void k_scatter(
    const int* __restrict__ esrc, const int* __restrict__ edst,
    unsigned* __restrict__ cursor, uint2* __restrict__ rec, int E, int R)
{
    const int e = blockIdx.x * 256 + threadIdx.x;
    const int r = blockIdx.y;
    if (e < E) {
        const size_t idx  = (size_t)r * E + e;
        const unsigned d  = (unsigned)edst[idx];
        const unsigned bin  = (d >> BUCKET_SHIFT) * R + r;
        const unsigned slot = atomicAdd(&cursor[bin], 1u);
        rec[slot] = make_uint2((unsigned)esrc[idx], d | ((unsigned)r << REL_SHIFT));
    }
}

// ---------------- compute ----------------
__global__ __launch_bounds__(256) void k_compute(
    const float* __restrict__ feat, const float* __restrict__ weight,
    const uint2* __restrict__ rec, const unsigned* __restrict__ base,
    float* __restrict__ out, int N, int R)
{
    __shared__ float acc[BUCKET_NODES * 64];      // 32 KB
    const int t = threadIdx.x, wave = t >> 6, lane = t & 63;
    const int b = blockIdx.x;

    for (int i = t; i < BUCKET_NODES * 16; i += 256)
        ((float4*)acc)[i] = make_float4(0.f, 0.f, 0.f, 0.f);
    __syncthreads();

    const unsigned s0 = base[(size_t)b * R];
    const unsigned s1 = base[(size_t)(b + 1) * R];   // bucket range (all rels)

    float wreg[64];
    int rcur = -1;

    for (unsigned chunk = s0 + (unsigned)wave * 64u; chunk < s1; chunk += 256u) {
        const int n = (int)min(64u, s1 - chunk);
        const uint2 rv = rec[chunk + (unsigned)min(lane, n - 1)];
        const unsigned myrel = (rv.y >> REL_SHIFT) & 7u;
        int i = 0;
        while (i < n) {                                  // relation runs
            const int r = (__builtin_amdgcn_readlane((int)rv.y, i) >> REL_SHIFT) & 7;
            unsigned long long neq = __ballot(myrel != (unsigned)r) >> i;
            int run = neq ? (int)__builtin_ctzll(neq) : (n - i);
            run = min(run, n - i);
            if (r != rcur) {                             // reload W column
                const float* wb = weight + (size_t)r * 4096 + lane;
                #pragma unroll
                for (int d = 0; d < 64; ++d) wreg[d] = wb[(size_t)d * 64];
                rcur = r;
            }
            const int jend = i + run;
            for (int j = i; j < jend; ++j) {
                const int srow = __builtin_amdgcn_readlane((int)rv.x, j);
                const int dloc = __builtin_amdgcn_readlane((int)rv.y, j) & (BUCKET_NODES - 1);
                const float4* xp = (const float4*)(feat + (size_t)srow * 64);
                float a0 = 0.f, a1 = 0.f, a2 = 0.f, a3 = 0.f;
                #pragma unroll
                for (int c = 0; c < 16; ++c) {
                    const float4 v = xp[c];              // uniform-addr bcast
                    a0 = fmaf(v.x, wreg[4 * c + 0], a0);
                    a1 = fmaf(v.y, wreg[4 * c + 1], a1);
                    a2 = fmaf(v.z, wreg[4 * c + 2], a2);
                    a3 = fmaf(v.w, wreg[4 * c + 3], a3);
                }
                atomicAdd(&acc[dloc * 64 + lane], (a0 + a1) + (a2 + a3));  // LDS
            }
            i = jend;
        }
    }

    __syncthreads();
    const int n0 = b << BUCKET_SHIFT;                  // flush: one store/elem
    for (int i = t; i < BUCKET_NODES * 16; i += 256) {
        const int row = i >> 4;
        if (n0 + row < N)
            ((float4*)(out + (size_t)(n0 + row) * 64))[i & 15] = ((float4*)acc)[i];
    }
}

// ---------------- fallback (R7 structure) if ws too small ----------------
#define FB_TILE_E 256
__global__ __launch_bounds__(256) void k_fallback(
    const float* __restrict__ feat, const float* __restrict__ weight,
    const int* __restrict__ esrc, const int* __restrict__ edst,
    float* __restrict__ out, int E, int blocksPerRel)
{
    const int t = threadIdx.x, wave = t >> 6, lane = t & 63;
    const int r = blockIdx.x / blocksPerRel;
    const int e0 = (blockIdx.x % blocksPerRel) * FB_TILE_E + wave * 64;
    if (e0 >= E) return;
    const float* wbase = weight + (size_t)r * 4096 + lane;
    float wreg[64];
    #pragma unroll
    for (int d = 0; d < 64; ++d) wreg[d] = wbase[(size_t)d * 64];
    const int nE = min(64, E - e0);
    const int ei = e0 + min(lane, nE - 1);
    const int sv = esrc[(size_t)r * E + ei];
    const int dv = edst[(size_t)r * E + ei];
    for (int i = 0; i < nE; ++i) {
        const int srow = __builtin_amdgcn_readlane(sv, i);
        const int drow = __builtin_amdgcn_readlane(dv, i);
        const float4* xp = (const float4*)(feat + (size_t)srow * 64);
        float a0 = 0.f, a1 = 0.f, a2 = 0.f, a3 = 0.f;
        #pragma unroll
        for (int c = 0; c < 16; ++c) {
            const float4 v = xp[c];
            a0 = fmaf(v.x, wreg[4 * c + 0], a0);
            a1 = fmaf(v.y, wreg[4 * c + 1], a1);
            a2 = fmaf(v.z, wreg[4 * c + 2], a2);
            a3 = fmaf(v.w, wreg[4 * c + 3], a3);
        }
        atomicAdd(out + (size_t)drow * 64 + lane, (a0 + a1) + (a2 + a3));
    }
}

extern "C" void kernel_launch(void* const* d_in, const int* in_sizes, int n_in,
                              void* d_out, int out_size, void* d_ws, size_t ws_size,
                              hipStream_t stream) {
    const float* feat   = (const float*)d_in[0];
    const float* weight = (const float*)d_in[1];
    const int*   esrc   = (const int*)d_in[2];
    const int*   edst   = (const int*)d_in[3];
    float*       out    = (float*)d_out;

    const int R = in_sizes[1] / 4096;            // weight [R,64,64]
    const int E = in_sizes[2] / R;               // edges  [R,E]
    const int N = in_sizes[0] / 64;              // feat   [N,64]
    const size_t RE = (size_t)R * E;
    const int NB    = (N + BUCKET_NODES - 1) / BUCKET_NODES;
    const int NBINS = NB * R;

    const size_t recBytes  = RE * sizeof(uint2);
    const size_t metaBytes = (size_t)(3 * NBINS + 2) * sizeof(unsigned);

    if (ws_size < recBytes + metaBytes) {        // safety fallback
        hipMemsetAsync(d_out, 0, (size_t)out_size * sizeof(float), stream);
        const int blocksPerRel = (E + FB_TILE_E - 1) / FB_TILE_E;
        k_fallback<<<dim3(R * blocksPerRel), 256, 0, stream>>>(
            feat, weight, esrc, edst, out, E, blocksPerRel);
        return;
    }

    uint2*    rec    = (uint2*)d_ws;
    unsigned* hist   = (unsigned*)((char*)d_ws + recBytes);
    unsigned* basep  = hist + NBINS;             // NBINS+1 entries
    unsigned* cursor = basep + NBINS + 1;

    hipMemsetAsync(hist, 0, (size_t)NBINS * sizeof(unsigned), stream);

    const dim3 eg((E + 255) / 256, R);
    k_hist   <<<eg, 256, 0, stream>>>(edst, hist, E, R);
    k_scan   <<<1, 256, 0, stream>>>(hist, basep, cursor, NBINS);
    k_scatter<<<eg, 256, 0, stream>>>(esrc, edst, cursor, rec, E, R);
    // buckets tile [0, NB*128) >= N: every out element written exactly once,
    // so no d_out memset needed on this path.
    k_compute<<<NB, 256, 0, stream>>>(feat, weight, rec, basep, out, N, R);
}